// Round 11
// baseline (194.898 us; speedup 1.0000x reference)
//
#include <hip/hip_runtime.h>
#include <hip/hip_bf16.h>

typedef __hip_bfloat16 bf16;
typedef __attribute__((ext_vector_type(8))) short short8;   // 8 bf16 = 4 VGPRs
typedef __attribute__((ext_vector_type(4))) float floatx4;  // MFMA C/D

#define SEQ 4096
#define DIM 1024
#define NH 16
#define HD 64

// exp2 directly on v_exp_f32 (Q is pre-scaled by log2(e)/8 in projection)
#if defined(__has_builtin)
#if __has_builtin(__builtin_amdgcn_exp2f)
#define EXP2(x) __builtin_amdgcn_exp2f(x)
#endif
#endif
#ifndef EXP2
#define EXP2(x) exp2f(x)
#endif

__device__ __forceinline__ short f2s(float f) { bf16 t = __float2bfloat16(f); return *(short*)&t; }
__device__ __forceinline__ float s2f(short s) { bf16 t = *(bf16*)&s; return __bfloat162float(t); }

// async global->LDS, 16B per lane; LDS dest = wave-uniform base + lane*16
__device__ __forceinline__ void gload16(const void* g, void* l) {
    __builtin_amdgcn_global_load_lds(
        (const __attribute__((address_space(1))) void*)g,
        (__attribute__((address_space(3))) void*)l, 16, 0, 0);
}

// Barrier that orders LDS ops only (no vmcnt drain): in-flight global->REG
// prefetch loads legally cross it; their consumers get compiler-inserted
// counted vmcnt waits. Writes drained BEFORE s_barrier => cross-wave visible.
__device__ __forceinline__ void barrier_lgkm() {
    asm volatile("s_waitcnt lgkmcnt(0)" ::: "memory");
    __builtin_amdgcn_s_barrier();
}

__device__ __forceinline__ short8 cvt8(float4 a, float4 b) {
    short8 s;
    s[0] = f2s(a.x); s[1] = f2s(a.y); s[2] = f2s(a.z); s[3] = f2s(a.w);
    s[4] = f2s(b.x); s[5] = f2s(b.y); s[6] = f2s(b.z); s[7] = f2s(b.w);
    return s;
}

// ---------------------------------------------------------------------------
// Transpose+cast: W fp32 [K][N] -> Wt bf16 [N][K]. blockIdx.z selects weight.
// ---------------------------------------------------------------------------
__global__ __launch_bounds__(256) void transpose_cast_kernel(
    const float* __restrict__ W0, const float* __restrict__ W1,
    const float* __restrict__ W2, const float* __restrict__ W3,
    bf16* __restrict__ Wt_all)
{
    const float* W = blockIdx.z == 0 ? W0 : blockIdx.z == 1 ? W1
                   : blockIdx.z == 2 ? W2 : W3;
    bf16* Wt = Wt_all + (size_t)blockIdx.z * DIM * DIM;

    __shared__ float tile[32][33];
    const int n0 = blockIdx.x * 32, k0 = blockIdx.y * 32;
    const int tr = threadIdx.x >> 5;
    const int tc = threadIdx.x & 31;
#pragma unroll
    for (int i = 0; i < 32; i += 8)
        tile[tr + i][tc] = W[(size_t)(k0 + tr + i) * DIM + n0 + tc];
    __syncthreads();
#pragma unroll
    for (int i = 0; i < 32; i += 8)
        Wt[(size_t)(n0 + tr + i) * DIM + k0 + tc] = __float2bfloat16(tile[tc][tr + i]);
}

// ---------------------------------------------------------------------------
// Fused QKV GEMM (round-1 version, measured good): C_z = x(fp32) @ Wt_z^T.
// 128x128 tile, BK=64, fp32-A DMA staging + cvt at fragment read, XOR swizzle.
// z==0 (Q) output pre-scaled by log2(e)/sqrt(HD) so attention uses raw exp2.
// ---------------------------------------------------------------------------
#define QBM 128
#define QBN 128
#define QBK 64

__global__ __launch_bounds__(256) void qkv_gemm_kernel(
    const float* __restrict__ A, const bf16* __restrict__ Wt,
    bf16* __restrict__ Qb, bf16* __restrict__ Kb, bf16* __restrict__ Vb)
{
    const int z = blockIdx.z;
    const bf16* Bt = Wt + (size_t)z * DIM * DIM;
    bf16* C = z == 0 ? Qb : (z == 1 ? Kb : Vb);
    const float osc = (z == 0) ? 0.18033688f : 1.0f;   // 0.125 * log2(e)

    __shared__ alignas(16) float Af[QBM][QBK];   // 32 KB, fp32
    __shared__ alignas(16) short Bs[QBN][QBK];   // 16 KB, bf16

    const int tid  = threadIdx.x;
    const int wave = tid >> 6, lane = tid & 63;
    const int l15  = lane & 15, quad = lane >> 4;
    const int wm = (wave & 1) * 64;
    const int wn = (wave >> 1) * 64;
    const int bm = blockIdx.y * QBM;
    const int bn = blockIdx.x * QBN;

    const int arow = tid >> 4;
    const int agch = (tid & 15) ^ (arow & 15);
    const float* gA = A + (size_t)(bm + arow) * DIM + agch * 4;
    char* ldsA = (char*)&Af[0][0] + wave * 1024;

    const int brow = tid >> 3;
    const int bgch = (tid & 7) ^ (brow & 7);
    const bf16* gB = Bt + (size_t)(bn + brow) * DIM + bgch * 8;
    char* ldsB = (char*)&Bs[0][0] + wave * 1024;

    floatx4 acc[4][4] = {};

    for (int k0 = 0; k0 < DIM; k0 += QBK) {
        __syncthreads();
#pragma unroll
        for (int c = 0; c < 8; ++c)
            gload16(gA + (size_t)c * 16 * DIM + k0, ldsA + c * 4096);
#pragma unroll
        for (int c = 0; c < 4; ++c)
            gload16(gB + (size_t)c * 32 * DIM + k0, ldsB + c * 4096);
        __syncthreads();

#pragma unroll
        for (int c2 = 0; c2 < 2; ++c2) {
            const int g0 = c2 * 8 + quad * 2;
            const int cb = (c2 * 4 + quad) ^ (l15 & 7);
            short8 afr[4], bfr[4];
#pragma unroll
            for (int i = 0; i < 4; ++i) {
                const int ra = wm + i * 16 + l15;
                float4 f0 = *(const float4*)&Af[ra][(g0 ^ l15) * 4];
                float4 f1 = *(const float4*)&Af[ra][((g0 + 1) ^ l15) * 4];
                afr[i] = cvt8(f0, f1);
                bfr[i] = *(const short8*)&Bs[wn + i * 16 + l15][cb * 8];
            }
#pragma unroll
            for (int mi = 0; mi < 4; ++mi)
#pragma unroll
                for (int ni = 0; ni < 4; ++ni)
                    acc[mi][ni] = __builtin_amdgcn_mfma_f32_16x16x32_bf16(
                        afr[mi], bfr[ni], acc[mi][ni], 0, 0, 0);
        }
    }

#pragma unroll
    for (int mi = 0; mi < 4; ++mi)
#pragma unroll
        for (int r = 0; r < 4; ++r) {
            const int row = bm + wm + mi * 16 + quad * 4 + r;
#pragma unroll
            for (int ni = 0; ni < 4; ++ni) {
                const int col = bn + wn + ni * 16 + l15;
                C[(size_t)row * DIM + col] = __float2bfloat16(acc[mi][ni][r] * osc);
            }
        }
}

// ---------------------------------------------------------------------------
// Final GEMM (unchanged): out = ctx(bf16) @ Wo^T + bias. 128x64 tile.
// ---------------------------------------------------------------------------
__global__ __launch_bounds__(256) void out_gemm_kernel(
    const bf16* __restrict__ A, const bf16* __restrict__ Bt,
    const float* __restrict__ bias, float* __restrict__ C)
{
    __shared__ alignas(16) short Asl[128][64];
    __shared__ alignas(16) short Bsl[64][64];

    const int tid  = threadIdx.x;
    const int wave = tid >> 6, lane = tid & 63;
    const int l15  = lane & 15, quad = lane >> 4;
    const int wm = (wave & 1) * 64;
    const int wn = (wave >> 1) * 32;
    const int bm = blockIdx.y * 128;
    const int bn = blockIdx.x * 64;

    const int srow   = tid >> 3;
    const int gchunk = (tid & 7) ^ (srow & 7);
    const bf16* gA = A  + (size_t)(bm + srow) * DIM + gchunk * 8;
    const bf16* gB = Bt + (size_t)(bn + srow) * DIM + gchunk * 8;
    char* ldsA = (char*)&Asl[0][0] + wave * 1024;
    char* ldsB = (char*)&Bsl[0][0] + wave * 1024;

    floatx4 acc[4][2] = {};

    for (int k0 = 0; k0 < DIM; k0 += 64) {
        __syncthreads();
#pragma unroll
        for (int c = 0; c < 4; ++c)
            gload16(gA + (size_t)c * 32 * DIM + k0, ldsA + c * 4096);
#pragma unroll
        for (int c = 0; c < 2; ++c)
            gload16(gB + (size_t)c * 32 * DIM + k0, ldsB + c * 4096);
        __syncthreads();

#pragma unroll
        for (int c2 = 0; c2 < 2; ++c2) {
            const int cb = (c2 * 4 + quad) ^ (l15 & 7);
            short8 afr[4], bfr[2];
#pragma unroll
            for (int i = 0; i < 4; ++i)
                afr[i] = *(const short8*)&Asl[wm + i * 16 + l15][cb * 8];
#pragma unroll
            for (int i = 0; i < 2; ++i)
                bfr[i] = *(const short8*)&Bsl[wn + i * 16 + l15][cb * 8];
#pragma unroll
            for (int mi = 0; mi < 4; ++mi)
#pragma unroll
                for (int ni = 0; ni < 2; ++ni)
                    acc[mi][ni] = __builtin_amdgcn_mfma_f32_16x16x32_bf16(
                        afr[mi], bfr[ni], acc[mi][ni], 0, 0, 0);
        }
    }

#pragma unroll
    for (int mi = 0; mi < 4; ++mi)
#pragma unroll
        for (int r = 0; r < 4; ++r) {
            const int row = bm + wm + mi * 16 + quad * 4 + r;
#pragma unroll
            for (int ni = 0; ni < 2; ++ni) {
                const int col = bn + wn + ni * 16 + l15;
                C[(size_t)row * DIM + col] = acc[mi][ni][r] + bias[col];
            }
        }
}

// ---------------------------------------------------------------------------
// Flash attention v15 = v13 (round-9, 53.9us) + BLOCK-LEVEL KEY-RANGE SPLIT.
// v13 was grid-starved: 512 blocks = 2/CU while LDS allows 4; per-block
// latency-bound (31% of LDS BW), so per-CU throughput scales with resident
// blocks. Split strips qj>=16 into kblock0 (tiles 0..qj, no mask) and
// kblock1 (tiles qj+1..2qj+1, owns diagonal). 768 blocks = 3/CU, all
// resident (LDS cap 4/CU); decode gives every CU {kb0(31-t), kb1(31-t),
// unsplit(t)} = (32-t)+(32-t)+(2t+2) = 66 tiles on EVERY CU; max serial
// depth 32 (was 64). PV/l are linear in keys -> partials exact.
//   mode A (kblock0): O0 partial (bf16) + l0 -> scratch (dead Wq/Wk region)
//   mode B (kblock1): O1 partial (bf16, unnormalized) -> ctx rows, l1 -> scratch
//   mode U (unsplit): normalize + write ctx (v13 path)
// combine_kernel (next launch; kernel boundary = ordering, no flags/spins)
// normalizes split rows: ctx = (O0+O1)/(l0+l1).
// v13 inner loop (key-split waves, reg staging, lgkm barriers, V-slot
// permutation, cross-kh LDS reduction) unchanged; buffer parity = (kt-kt0)&1.
// ---------------------------------------------------------------------------
#define QT 128
#define KT 64
#define LDT 72

__global__ __launch_bounds__(512, 4) void flash_attn_kernel(
    const bf16* __restrict__ Q, const bf16* __restrict__ K,
    const bf16* __restrict__ V, bf16* ctx,
    bf16* __restrict__ O0buf, float* __restrict__ l0buf,
    float* __restrict__ l1buf)
{
    const int blk = blockIdx.x;            // 0..767
    const int g   = blk >> 8;              // 0: kblock0, 1: kblock1, 2: unsplit
    const int i   = blk & 255;
    const int t   = i & 15, h = i >> 4;

    int qj, kt0, kt1;
    if (g == 2) { qj = t;      kt0 = 0;      kt1 = 2 * t + 2; }
    else        { qj = 31 - t; kt0 = g ? (qj + 1) : 0;
                               kt1 = g ? (2 * qj + 2) : (qj + 1); }
    const int nkt = 2 * qj + 2;            // global tile count (for masking)
    const int q0  = qj * QT;
    const int sp  = (15 - t) * 16 + h;     // scratch strip index (splits only)

    const int tid  = threadIdx.x;          // 0..511
    const int wave = tid >> 6;             // 0..7
    const int qg   = wave & 3;             // q-row group: rows qg*32..+31
    const int kh   = wave >> 2;            // key half: keys kh*32..+31
    const int lane = tid & 63;
    const int l15  = lane & 15;
    const int quad = lane >> 4;

    // K/V double buffers; after the loop the same space is reused for the
    // cross-half O/l reduction (32KB + 512B <= 36864B).
    __shared__ alignas(16) char smem[36864];
    short (*Ks)[KT][LDT] = (short (*)[KT][LDT])smem;            // [2][64][72]
    short (*Vt)[HD][LDT] = (short (*)[HD][LDT])(smem + 18432);  // [2][64][72]
    float* redO = (float*)smem;            // 8192 floats = 32 KB
    float* redL = (float*)(smem + 32768);  // 128 floats

    // ---- Q fragments straight from global (no LDS); 32 rows per wave ----
    // NOTE: mode-B blocks later overwrite ctx(=Q) rows with O1 partials.
    // Safe: all 768 blocks are co-resident (3/CU <= LDS cap 4/CU) and g=0
    // blocks dispatch first, so every prologue Q-read completes ~us before
    // any epilogue write (epilogues follow >=17 tiles of work).
    short8 qfrag[2][2];
#pragma unroll
    for (int s = 0; s < 2; ++s) {
        const bf16* qp = Q + (size_t)(q0 + qg * 32 + s * 16 + l15) * DIM
                       + h * HD + quad * 8;
        qfrag[s][0] = *(const short8*)(qp);
        qfrag[s][1] = *(const short8*)(qp + 32);
    }

    // K staging: 512 threads, one 16B unit: row tid>>3 (0..63), chunk (tid&7)*8
    const int kr = tid >> 3, kc = (tid & 7) * 8;
    // V staging: threads 0..255 (keys vr,vr+1 x dims vd..vd+7)
    const bool vstager = tid < 256;
    const int vr = (tid & 31) * 2, vd = ((tid >> 5) & 7) * 8;
    // key -> PV slot within its 32-key half: col = (key&32) + [k3 k2 k4 k1 k0]
    const int vcol = (vr & 32) + ((vr >> 2) & 3) * 8
                   + ((vr >> 4) & 1) * 4 + (vr & 3);

    // ---- load tile kt0 regs, write straight to buf0 ----
    short8 kreg, vreg0, vreg1;
    {
        const size_t kb = (size_t)kt0 * KT;
        kreg = *(const short8*)(K + (kb + kr) * DIM + h * HD + kc);
        if (vstager) {
            vreg0 = *(const short8*)(V + (kb + vr) * DIM + h * HD + vd);
            vreg1 = *(const short8*)(V + (kb + vr + 1) * DIM + h * HD + vd);
        }
    }
    *(short8*)&Ks[0][kr][kc] = kreg;
    if (vstager) {
#pragma unroll
        for (int i2 = 0; i2 < 8; ++i2) {
            unsigned int pv = (unsigned int)(unsigned short)vreg0[i2]
                            | ((unsigned int)(unsigned short)vreg1[i2] << 16);
            *(unsigned int*)&Vt[0][vd + i2][vcol] = pv;
        }
    }
    // ---- prefetch tile kt0+1 regs (every mode has >= 2 tiles) ----
    {
        const size_t kb = (size_t)(kt0 + 1) * KT;
        kreg = *(const short8*)(K + (kb + kr) * DIM + h * HD + kc);
        if (vstager) {
            vreg0 = *(const short8*)(V + (kb + vr) * DIM + h * HD + vd);
            vreg1 = *(const short8*)(V + (kb + vr + 1) * DIM + h * HD + vd);
        }
    }

    barrier_lgkm();   // buf0 ds_writes visible; prefetch loads stay in flight

    short8 onesf;
#pragma unroll
    for (int i2 = 0; i2 < 8; ++i2) onesf[i2] = (short)0x3F80;   // bf16 1.0

    floatx4 o_acc[2][4] = {};
    floatx4 lacc[2] = {};

    for (int kt = kt0; kt < kt1; ++kt) {
        const int b = (kt - kt0) & 1;

        // ---- S^T (this wave's 32 keys): D[m=key kh*32+n*16+quad*4+r][qrow l15]
        floatx4 sT[2][2] = {};
#pragma unroll
        for (int n = 0; n < 2; ++n)
#pragma unroll
            for (int c = 0; c < 2; ++c) {
                short8 kf = *(const short8*)
                    &Ks[b][kh * 32 + n * 16 + l15][c * 32 + quad * 8];
#pragma unroll
                for (int s = 0; s < 2; ++s)
                    sT[s][n] = __builtin_amdgcn_mfma_f32_16x16x32_bf16(
                        kf, qfrag[s][c], sT[s][n], 0, 0, 0);
            }

        // ---- stage tile kt+1 into buf[b^1] early; prefetch tile kt+2 ----
        if (kt + 1 < kt1) {
            *(short8*)&Ks[b ^ 1][kr][kc] = kreg;
            if (vstager) {
#pragma unroll
                for (int i2 = 0; i2 < 8; ++i2) {
                    unsigned int pv = (unsigned int)(unsigned short)vreg0[i2]
                                    | ((unsigned int)(unsigned short)vreg1[i2] << 16);
                    *(unsigned int*)&Vt[b ^ 1][vd + i2][vcol] = pv;
                }
            }
            if (kt + 2 < kt1) {
                const size_t nb = (size_t)(kt + 2) * KT;
                kreg = *(const short8*)(K + (nb + kr) * DIM + h * HD + kc);
                if (vstager) {
                    vreg0 = *(const short8*)(V + (nb + vr) * DIM + h * HD + vd);
                    vreg1 = *(const short8*)(V + (nb + vr + 1) * DIM + h * HD + vd);
                }
            }
        }

        // ---- P = exp2(S^T) in-register -> PV A-fragment (slot j = n*4+r) ----
        short8 pfrag[2];
        const int kbase = kt * KT + kh * 32;
        if (kt >= nkt - 2) {
#pragma unroll
            for (int s = 0; s < 2; ++s) {
                const int qrow = q0 + qg * 32 + s * 16 + l15;
                float p[2][4];
#pragma unroll
                for (int n = 0; n < 2; ++n) {
                    const int key0 = kbase + n * 16 + quad * 4;
#pragma unroll
                    for (int r = 0; r < 4; ++r)
                        p[n][r] = (key0 + r <= qrow) ? EXP2(sT[s][n][r]) : 0.f;
                }
                short8 f;
#pragma unroll
                for (int j = 0; j < 8; ++j)
                    f[j] = f2s(p[j >> 2][j & 3]);
                pfrag[s] = f;
            }
        } else {
#pragma unroll
            for (int s = 0; s < 2; ++s) {
                short8 f;
#pragma unroll
                for (int j = 0; j < 8; ++j)
                    f[j] = f2s(EXP2(sT[s][j >> 2][j & 3]));
                pfrag[s] = f;
            }
        }

        // ---- O += P V (this key half only) ; l += P . 1 ----
#pragma unroll
        for (int n = 0; n < 4; ++n) {
            short8 vf = *(const short8*)
                &Vt[b][n * 16 + l15][kh * 32 + quad * 8];
#pragma unroll
            for (int s = 0; s < 2; ++s)
                o_acc[s][n] = __builtin_amdgcn_mfma_f32_16x16x32_bf16(
                    pfrag[s], vf, o_acc[s][n], 0, 0, 0);
        }
#pragma unroll
        for (int s = 0; s < 2; ++s)
            lacc[s] = __builtin_amdgcn_mfma_f32_16x16x32_bf16(
                pfrag[s], onesf, lacc[s], 0, 0, 0);

        barrier_lgkm();   // buf[b^1] ds-visible; reads of buf[b] complete;
                          // kt+2 global prefetch stays in flight
    }

    // ---- cross-half reduction: kh=1 partials -> LDS -> kh=0 adds ----
    if (kh == 1) {
#pragma unroll
        for (int s = 0; s < 2; ++s)
#pragma unroll
            for (int n = 0; n < 4; ++n)
#pragma unroll
                for (int r = 0; r < 4; ++r)
                    redO[(size_t)(qg * 32 + s * 16 + quad * 4 + r) * 64
                         + n * 16 + l15] = o_acc[s][n][r];
        if (l15 == 0) {
#pragma unroll
            for (int s = 0; s < 2; ++s)
#pragma unroll
                for (int r = 0; r < 4; ++r)
                    redL[qg * 32 + s * 16 + quad * 4 + r] = lacc[s][r];
        }
    }
    __syncthreads();
    if (kh == 0) {
#pragma unroll
        for (int s = 0; s < 2; ++s)
#pragma unroll
            for (int r = 0; r < 4; ++r) {
                const int row_l = qg * 32 + s * 16 + quad * 4 + r;
                const float lsum = lacc[s][r] + redL[row_l];
                if (g == 2) {
                    // mode U: normalize, write ctx
                    const float inv = 1.0f / lsum;
                    const int row = q0 + row_l;
#pragma unroll
                    for (int n = 0; n < 4; ++n) {
                        const float o = o_acc[s][n][r]
                                      + redO[(size_t)row_l * 64 + n * 16 + l15];
                        ctx[(size_t)row * DIM + h * HD + n * 16 + l15] =
                            __float2bfloat16(o * inv);
                    }
                } else if (g == 0) {
                    // mode A: partial -> scratch
#pragma unroll
                    for (int n = 0; n < 4; ++n) {
                        const float o = o_acc[s][n][r]
                                      + redO[(size_t)row_l * 64 + n * 16 + l15];
                        O0buf[(size_t)sp * 8192 + row_l * 64 + n * 16 + l15] =
                            __float2bfloat16(o);
                    }
                    if (l15 == 0) l0buf[sp * 128 + row_l] = lsum;
                } else {
                    // mode B: unnormalized partial -> ctx rows; l1 -> scratch
                    const int row = q0 + row_l;
#pragma unroll
                    for (int n = 0; n < 4; ++n) {
                        const float o = o_acc[s][n][r]
                                      + redO[(size_t)row_l * 64 + n * 16 + l15];
                        ctx[(size_t)row * DIM + h * HD + n * 16 + l15] =
                            __float2bfloat16(o);
                    }
                    if (l15 == 0) l1buf[sp * 128 + row_l] = lsum;
                }
            }
    }
}

// ---------------------------------------------------------------------------
// Combine: for split strips (qj>=16), ctx = (O0 + O1_in_ctx) / (l0 + l1).
// 256 strips x 128 rows x 64 dims; one short8 per thread -> 262144 threads.
// ---------------------------------------------------------------------------
__global__ __launch_bounds__(512) void combine_kernel(
    const bf16* __restrict__ O0buf, const float* __restrict__ l0buf,
    const float* __restrict__ l1buf, bf16* __restrict__ ctx)
{
    const int tid = blockIdx.x * 512 + threadIdx.x;   // 0..262143
    const int d8  = tid & 7;
    const int row = (tid >> 3) & 127;
    const int sp  = tid >> 10;                        // 0..255
    const int strip = 16 + (sp >> 4), h = sp & 15;

    const float inv = 1.0f / (l0buf[sp * 128 + row] + l1buf[sp * 128 + row]);
    const short8 a = *(const short8*)&O0buf[(size_t)sp * 8192 + row * 64 + d8 * 8];
    bf16* cp = ctx + (size_t)(strip * 128 + row) * DIM + h * HD + d8 * 8;
    short8 c = *(const short8*)cp;
    short8 o;
#pragma unroll
    for (int j = 0; j < 8; ++j)
        o[j] = f2s((s2f(a[j]) + s2f(c[j])) * inv);
    *(short8*)cp = o;
}

// ---------------------------------------------------------------------------
// Memory plan (16 MB ws):
//   ws[0 : 8MB]  = Wt_all (4 x bf16 [N][K]: Wq,Wk,Wv,Wo)
//                  after qkv, Wq/Wk/Wv region is dead ->
//                  ws[0:4MB] = O0 partials (bf16 [256][128][64])
//                  ws[4MB:+128KB] = l0 (fp32 [256][128]); then l1 (+128KB)
//                  ws[6:8MB] = Wo (stays live for out_gemm)
//   ws[8 : 16MB] = Q (bf16) -> ctx (in-place, alias-safe)
//   d_out[0:8MB] (bf16) = V scratch; d_out[8:16MB] = K scratch
// x is read directly (fp32) by the fused QKV GEMM — no cast, no alias.
// ---------------------------------------------------------------------------
extern "C" void kernel_launch(void* const* d_in, const int* in_sizes, int n_in,
                              void* d_out, int out_size, void* d_ws, size_t ws_size,
                              hipStream_t stream)
{
    const float* x  = (const float*)d_in[0];
    const float* Wq = (const float*)d_in[1];
    const float* Wk = (const float*)d_in[2];
    const float* Wv = (const float*)d_in[3];
    const float* Wo = (const float*)d_in[4];
    const float* bo = (const float*)d_in[5];
    float* out = (float*)d_out;

    bf16* Wt_all = (bf16*)d_ws;
    bf16* Qb     = Wt_all + (size_t)4 * DIM * DIM;    // ws + 8MB
    bf16* V      = (bf16*)d_out;                      // d_out[0:8MB]
    bf16* Kb     = V + (size_t)SEQ * DIM;             // d_out[8:16MB]
    bf16* ctx    = Qb;                                // in-place over Q
    const bf16* Wot = Wt_all + (size_t)3 * DIM * DIM;

    bf16*  O0buf = (bf16*)d_ws;                               // ws[0:4MB]
    float* l0buf = (float*)((char*)d_ws + (4u << 20));        // +128KB
    float* l1buf = (float*)((char*)d_ws + (4u << 20) + (128u << 10));

    transpose_cast_kernel<<<dim3(32, 32, 4), 256, 0, stream>>>(Wq, Wk, Wv, Wo, Wt_all);

    qkv_gemm_kernel<<<dim3(DIM / QBN, SEQ / QBM, 3), 256, 0, stream>>>(
        x, Wt_all, Qb, Kb, V);

    flash_attn_kernel<<<dim3(768), 512, 0, stream>>>(
        Qb, Kb, V, ctx, O0buf, l0buf, l1buf);

    combine_kernel<<<dim3(512), 512, 0, stream>>>(O0buf, l0buf, l1buf, ctx);

    out_gemm_kernel<<<dim3(DIM / 64, SEQ / 128), 256, 0, stream>>>(
        ctx, Wot, bo, out);
}

// Round 12
// 188.464 us; speedup vs baseline: 1.0341x; 1.0341x over previous
//
#include <hip/hip_runtime.h>
#include <hip/hip_bf16.h>

typedef __hip_bfloat16 bf16;
typedef __attribute__((ext_vector_type(8))) short short8;   // 8 bf16 = 4 VGPRs
typedef __attribute__((ext_vector_type(4))) float floatx4;  // MFMA C/D

#define SEQ 4096
#define DIM 1024
#define NH 16
#define HD 64

// exp2 directly on v_exp_f32 (Q is pre-scaled by log2(e)/8 in projection)
#if defined(__has_builtin)
#if __has_builtin(__builtin_amdgcn_exp2f)
#define EXP2(x) __builtin_amdgcn_exp2f(x)
#endif
#endif
#ifndef EXP2
#define EXP2(x) exp2f(x)
#endif

__device__ __forceinline__ short f2s(float f) { bf16 t = __float2bfloat16(f); return *(short*)&t; }

// async global->LDS, 16B per lane; LDS dest = wave-uniform base + lane*16
__device__ __forceinline__ void gload16(const void* g, void* l) {
    __builtin_amdgcn_global_load_lds(
        (const __attribute__((address_space(1))) void*)g,
        (__attribute__((address_space(3))) void*)l, 16, 0, 0);
}

// Barrier that orders LDS ops only (no vmcnt drain): in-flight global->REG
// prefetch loads legally cross it; their consumers get compiler-inserted
// counted vmcnt waits. Writes drained BEFORE s_barrier => cross-wave visible.
__device__ __forceinline__ void barrier_lgkm() {
    asm volatile("s_waitcnt lgkmcnt(0)" ::: "memory");
    __builtin_amdgcn_s_barrier();
}

__device__ __forceinline__ short8 cvt8(float4 a, float4 b) {
    short8 s;
    s[0] = f2s(a.x); s[1] = f2s(a.y); s[2] = f2s(a.z); s[3] = f2s(a.w);
    s[4] = f2s(b.x); s[5] = f2s(b.y); s[6] = f2s(b.z); s[7] = f2s(b.w);
    return s;
}

// ---------------------------------------------------------------------------
// Transpose+cast: W fp32 [K][N] -> Wt bf16 [N][K]. blockIdx.z selects weight.
// ---------------------------------------------------------------------------
__global__ __launch_bounds__(256) void transpose_cast_kernel(
    const float* __restrict__ W0, const float* __restrict__ W1,
    const float* __restrict__ W2, const float* __restrict__ W3,
    bf16* __restrict__ Wt_all)
{
    const float* W = blockIdx.z == 0 ? W0 : blockIdx.z == 1 ? W1
                   : blockIdx.z == 2 ? W2 : W3;
    bf16* Wt = Wt_all + (size_t)blockIdx.z * DIM * DIM;

    __shared__ float tile[32][33];
    const int n0 = blockIdx.x * 32, k0 = blockIdx.y * 32;
    const int tr = threadIdx.x >> 5;
    const int tc = threadIdx.x & 31;
#pragma unroll
    for (int i = 0; i < 32; i += 8)
        tile[tr + i][tc] = W[(size_t)(k0 + tr + i) * DIM + n0 + tc];
    __syncthreads();
#pragma unroll
    for (int i = 0; i < 32; i += 8)
        Wt[(size_t)(n0 + tr + i) * DIM + k0 + tc] = __float2bfloat16(tile[tc][tr + i]);
}

// ---------------------------------------------------------------------------
// Fused QKV GEMM (round-1 version, measured good): C_z = x(fp32) @ Wt_z^T.
// 128x128 tile, BK=64, fp32-A DMA staging + cvt at fragment read, XOR swizzle.
// z==0 (Q) output pre-scaled by log2(e)/sqrt(HD) so attention uses raw exp2.
// ---------------------------------------------------------------------------
#define QBM 128
#define QBN 128
#define QBK 64

__global__ __launch_bounds__(256) void qkv_gemm_kernel(
    const float* __restrict__ A, const bf16* __restrict__ Wt,
    bf16* __restrict__ Qb, bf16* __restrict__ Kb, bf16* __restrict__ Vb)
{
    const int z = blockIdx.z;
    const bf16* Bt = Wt + (size_t)z * DIM * DIM;
    bf16* C = z == 0 ? Qb : (z == 1 ? Kb : Vb);
    const float osc = (z == 0) ? 0.18033688f : 1.0f;   // 0.125 * log2(e)

    __shared__ alignas(16) float Af[QBM][QBK];   // 32 KB, fp32
    __shared__ alignas(16) short Bs[QBN][QBK];   // 16 KB, bf16

    const int tid  = threadIdx.x;
    const int wave = tid >> 6, lane = tid & 63;
    const int l15  = lane & 15, quad = lane >> 4;
    const int wm = (wave & 1) * 64;
    const int wn = (wave >> 1) * 64;
    const int bm = blockIdx.y * QBM;
    const int bn = blockIdx.x * QBN;

    const int arow = tid >> 4;
    const int agch = (tid & 15) ^ (arow & 15);
    const float* gA = A + (size_t)(bm + arow) * DIM + agch * 4;
    char* ldsA = (char*)&Af[0][0] + wave * 1024;

    const int brow = tid >> 3;
    const int bgch = (tid & 7) ^ (brow & 7);
    const bf16* gB = Bt + (size_t)(bn + brow) * DIM + bgch * 8;
    char* ldsB = (char*)&Bs[0][0] + wave * 1024;

    floatx4 acc[4][4] = {};

    for (int k0 = 0; k0 < DIM; k0 += QBK) {
        __syncthreads();
#pragma unroll
        for (int c = 0; c < 8; ++c)
            gload16(gA + (size_t)c * 16 * DIM + k0, ldsA + c * 4096);
#pragma unroll
        for (int c = 0; c < 4; ++c)
            gload16(gB + (size_t)c * 32 * DIM + k0, ldsB + c * 4096);
        __syncthreads();

#pragma unroll
        for (int c2 = 0; c2 < 2; ++c2) {
            const int g0 = c2 * 8 + quad * 2;
            const int cb = (c2 * 4 + quad) ^ (l15 & 7);
            short8 afr[4], bfr[4];
#pragma unroll
            for (int i = 0; i < 4; ++i) {
                const int ra = wm + i * 16 + l15;
                float4 f0 = *(const float4*)&Af[ra][(g0 ^ l15) * 4];
                float4 f1 = *(const float4*)&Af[ra][((g0 + 1) ^ l15) * 4];
                afr[i] = cvt8(f0, f1);
                bfr[i] = *(const short8*)&Bs[wn + i * 16 + l15][cb * 8];
            }
#pragma unroll
            for (int mi = 0; mi < 4; ++mi)
#pragma unroll
                for (int ni = 0; ni < 4; ++ni)
                    acc[mi][ni] = __builtin_amdgcn_mfma_f32_16x16x32_bf16(
                        afr[mi], bfr[ni], acc[mi][ni], 0, 0, 0);
        }
    }

#pragma unroll
    for (int mi = 0; mi < 4; ++mi)
#pragma unroll
        for (int r = 0; r < 4; ++r) {
            const int row = bm + wm + mi * 16 + quad * 4 + r;
#pragma unroll
            for (int ni = 0; ni < 4; ++ni) {
                const int col = bn + wn + ni * 16 + l15;
                C[(size_t)row * DIM + col] = __float2bfloat16(acc[mi][ni][r] * osc);
            }
        }
}

// ---------------------------------------------------------------------------
// Final GEMM (unchanged): out = ctx(bf16) @ Wo^T + bias. 128x64 tile.
// ---------------------------------------------------------------------------
__global__ __launch_bounds__(256) void out_gemm_kernel(
    const bf16* __restrict__ A, const bf16* __restrict__ Bt,
    const float* __restrict__ bias, float* __restrict__ C)
{
    __shared__ alignas(16) short Asl[128][64];
    __shared__ alignas(16) short Bsl[64][64];

    const int tid  = threadIdx.x;
    const int wave = tid >> 6, lane = tid & 63;
    const int l15  = lane & 15, quad = lane >> 4;
    const int wm = (wave & 1) * 64;
    const int wn = (wave >> 1) * 32;
    const int bm = blockIdx.y * 128;
    const int bn = blockIdx.x * 64;

    const int srow   = tid >> 3;
    const int gchunk = (tid & 7) ^ (srow & 7);
    const bf16* gA = A  + (size_t)(bm + srow) * DIM + gchunk * 8;
    const bf16* gB = Bt + (size_t)(bn + srow) * DIM + gchunk * 8;
    char* ldsA = (char*)&Asl[0][0] + wave * 1024;
    char* ldsB = (char*)&Bsl[0][0] + wave * 1024;

    floatx4 acc[4][2] = {};

    for (int k0 = 0; k0 < DIM; k0 += 64) {
        __syncthreads();
#pragma unroll
        for (int c = 0; c < 4; ++c)
            gload16(gA + (size_t)c * 32 * DIM + k0, ldsA + c * 4096);
#pragma unroll
        for (int c = 0; c < 2; ++c)
            gload16(gB + (size_t)c * 32 * DIM + k0, ldsB + c * 4096);
        __syncthreads();

#pragma unroll
        for (int c2 = 0; c2 < 2; ++c2) {
            const int cb = (c2 * 4 + quad) ^ (l15 & 7);
            short8 afr[4], bfr[2];
#pragma unroll
            for (int i = 0; i < 4; ++i)
                afr[i] = *(const short8*)&Asl[wm + i * 16 + l15][cb * 8];
#pragma unroll
            for (int i = 0; i < 2; ++i)
                bfr[i] = *(const short8*)&Bsl[wn + i * 16 + l15][cb * 8];
#pragma unroll
            for (int mi = 0; mi < 4; ++mi)
#pragma unroll
                for (int ni = 0; ni < 2; ++ni)
                    acc[mi][ni] = __builtin_amdgcn_mfma_f32_16x16x32_bf16(
                        afr[mi], bfr[ni], acc[mi][ni], 0, 0, 0);
        }
    }

#pragma unroll
    for (int mi = 0; mi < 4; ++mi)
#pragma unroll
        for (int r = 0; r < 4; ++r) {
            const int row = bm + wm + mi * 16 + quad * 4 + r;
#pragma unroll
            for (int ni = 0; ni < 2; ++ni) {
                const int col = bn + wn + ni * 16 + l15;
                C[(size_t)row * DIM + col] = acc[mi][ni][r] + bias[col];
            }
        }
}

// ---------------------------------------------------------------------------
// Flash attention v16 = v13 (round-9, 53.9us) + LDS-ISSUE reduction + setprio.
//  - Diagnosis (r11): per-CU tile throughput ~2000cy regardless of resident
//    blocks; LDS *instruction issue* is the binding pipe. V staging was 16x
//    ds_write_b32/thread (256B per wave-inst) = 64 wave-insts/block-tile.
//  - Fix: 128 V-stager threads each own 4 consecutive keys x 8 dims; the
//    slot permutation [k5 k3 k2 k4 k1 k0] maps a key-quad (k1k0=0..3) to 4
//    CONTIGUOUS slots -> one aligned ds_write_b64 per dim. 8 b64/thread,
//    16 wave-insts/block-tile (4x fewer), bytes unchanged.
//  - s_setprio(1) around QK and PV MFMA clusters (T5: +4-7% attn, m191 —
//    two independent resident blocks give the scheduler arbitration room).
// Everything else identical to v13: key-split waves (4 qg x 2 kh), K DMA-free
// reg staging, double-buffer, lgkm-only barriers, exp2, complementary
// pairing, cross-kh LDS reduction.
// ---------------------------------------------------------------------------
#define QT 128
#define KT 64
#define LDT 72

__global__ __launch_bounds__(512, 4) void flash_attn_kernel(
    const bf16* __restrict__ Q, const bf16* __restrict__ K,
    const bf16* __restrict__ V, bf16* ctx)
{
    const int lin  = blockIdx.y * 32 + blockIdx.x;
    const int half = lin >> 8, idx = lin & 255;
    const int qj   = half ? (idx & 31) : 31 - (idx & 31);
    const int h    = (idx >> 5) + 8 * half;
    const int q0   = qj * QT;
    const int nkt  = 2 * qj + 2;

    const int tid  = threadIdx.x;          // 0..511
    const int wave = tid >> 6;             // 0..7
    const int qg   = wave & 3;             // q-row group: rows qg*32..+31
    const int kh   = wave >> 2;            // key half: keys kh*32..+31
    const int lane = tid & 63;
    const int l15  = lane & 15;
    const int quad = lane >> 4;

    // K/V double buffers; after the loop the same space is reused for the
    // cross-half O/l reduction (32KB + 512B <= 36864B).
    __shared__ alignas(16) char smem[36864];
    short (*Ks)[KT][LDT] = (short (*)[KT][LDT])smem;            // [2][64][72]
    short (*Vt)[HD][LDT] = (short (*)[HD][LDT])(smem + 18432);  // [2][64][72]
    float* redO = (float*)smem;            // 8192 floats = 32 KB
    float* redL = (float*)(smem + 32768);  // 128 floats

    // ---- Q fragments straight from global (no LDS); 32 rows per wave ----
    short8 qfrag[2][2];
#pragma unroll
    for (int s = 0; s < 2; ++s) {
        const bf16* qp = Q + (size_t)(q0 + qg * 32 + s * 16 + l15) * DIM
                       + h * HD + quad * 8;
        qfrag[s][0] = *(const short8*)(qp);
        qfrag[s][1] = *(const short8*)(qp + 32);
    }

    // K staging: 512 threads, one 16B unit: row tid>>3 (0..63), chunk (tid&7)*8
    const int kr = tid >> 3, kc = (tid & 7) * 8;
    // V staging: threads 0..127: key quad vkg (keys vkg*4..+3), dim octet vdo
    // key->slot perm [k5 k3 k2 k4 k1 k0]; key-quad => 4 contiguous slots.
    const bool vstager = tid < 128;
    const int vkg = tid & 15, vdo = tid >> 4;          // vdo 0..7
    const int vcol = ((vkg >> 3) & 1) * 32 + ((vkg >> 1) & 1) * 16
                   + (vkg & 1) * 8 + ((vkg >> 2) & 1) * 4;

    short8 kreg, vregs[4];

#define LOAD_KV(kb) do {                                                      \
    kreg = *(const short8*)(K + (size_t)((kb) + kr) * DIM + h * HD + kc);     \
    if (vstager) {                                                            \
        _Pragma("unroll")                                                     \
        for (int _j = 0; _j < 4; ++_j)                                        \
            vregs[_j] = *(const short8*)                                      \
                (V + (size_t)((kb) + vkg * 4 + _j) * DIM + h * HD + vdo * 8); \
    }                                                                         \
} while (0)

#define STAGE_KV(buf) do {                                                    \
    *(short8*)&Ks[buf][kr][kc] = kreg;                                        \
    if (vstager) {                                                            \
        _Pragma("unroll")                                                     \
        for (int _i = 0; _i < 8; ++_i) {                                      \
            unsigned long long _u =                                           \
                  (unsigned long long)(unsigned short)vregs[0][_i]            \
                | ((unsigned long long)(unsigned short)vregs[1][_i] << 16)    \
                | ((unsigned long long)(unsigned short)vregs[2][_i] << 32)    \
                | ((unsigned long long)(unsigned short)vregs[3][_i] << 48);   \
            *(unsigned long long*)&Vt[buf][vdo * 8 + _i][vcol] = _u;          \
        }                                                                     \
    }                                                                         \
} while (0)

    // ---- tile 0 -> buf0; prefetch tile 1 regs (nkt >= 2 always) ----
    LOAD_KV(0);
    STAGE_KV(0);
    LOAD_KV(KT);

    barrier_lgkm();   // buf0 ds_writes visible; tile-1 loads stay in flight

    short8 onesf;
#pragma unroll
    for (int i2 = 0; i2 < 8; ++i2) onesf[i2] = (short)0x3F80;   // bf16 1.0

    floatx4 o_acc[2][4] = {};
    floatx4 lacc[2] = {};

    for (int kt = 0; kt < nkt; ++kt) {
        const int b = kt & 1;

        // ---- S^T (this wave's 32 keys): D[m=key kh*32+n*16+quad*4+r][qrow l15]
        floatx4 sT[2][2] = {};
        __builtin_amdgcn_s_setprio(1);
#pragma unroll
        for (int n = 0; n < 2; ++n)
#pragma unroll
            for (int c = 0; c < 2; ++c) {
                short8 kf = *(const short8*)
                    &Ks[b][kh * 32 + n * 16 + l15][c * 32 + quad * 8];
#pragma unroll
                for (int s = 0; s < 2; ++s)
                    sT[s][n] = __builtin_amdgcn_mfma_f32_16x16x32_bf16(
                        kf, qfrag[s][c], sT[s][n], 0, 0, 0);
            }
        __builtin_amdgcn_s_setprio(0);

        // ---- stage tile kt+1 into buf[b^1] early; prefetch tile kt+2 ----
        if (kt + 1 < nkt) {
            STAGE_KV(b ^ 1);
            if (kt + 2 < nkt) LOAD_KV((size_t)(kt + 2) * KT);
        }

        // ---- P = exp2(S^T) in-register -> PV A-fragment (slot j = n*4+r) ----
        short8 pfrag[2];
        const int kbase = kt * KT + kh * 32;
        if (kt >= nkt - 2) {
#pragma unroll
            for (int s = 0; s < 2; ++s) {
                const int qrow = q0 + qg * 32 + s * 16 + l15;
                float p[2][4];
#pragma unroll
                for (int n = 0; n < 2; ++n) {
                    const int key0 = kbase + n * 16 + quad * 4;
#pragma unroll
                    for (int r = 0; r < 4; ++r)
                        p[n][r] = (key0 + r <= qrow) ? EXP2(sT[s][n][r]) : 0.f;
                }
                short8 f;
#pragma unroll
                for (int j = 0; j < 8; ++j)
                    f[j] = f2s(p[j >> 2][j & 3]);
                pfrag[s] = f;
            }
        } else {
#pragma unroll
            for (int s = 0; s < 2; ++s) {
                short8 f;
#pragma unroll
                for (int j = 0; j < 8; ++j)
                    f[j] = f2s(EXP2(sT[s][j >> 2][j & 3]));
                pfrag[s] = f;
            }
        }

        // ---- O += P V (this key half only) ; l += P . 1 ----
        __builtin_amdgcn_s_setprio(1);
#pragma unroll
        for (int n = 0; n < 4; ++n) {
            short8 vf = *(const short8*)
                &Vt[b][n * 16 + l15][kh * 32 + quad * 8];
#pragma unroll
            for (int s = 0; s < 2; ++s)
                o_acc[s][n] = __builtin_amdgcn_mfma_f32_16x16x32_bf16(
                    pfrag[s], vf, o_acc[s][n], 0, 0, 0);
        }
#pragma unroll
        for (int s = 0; s < 2; ++s)
            lacc[s] = __builtin_amdgcn_mfma_f32_16x16x32_bf16(
                pfrag[s], onesf, lacc[s], 0, 0, 0);
        __builtin_amdgcn_s_setprio(0);

        barrier_lgkm();   // buf[b^1] ds-visible; reads of buf[b] complete;
                          // kt+2 global prefetch stays in flight
    }

    // ---- cross-half reduction: kh=1 partials -> LDS -> kh=0 adds ----
    if (kh == 1) {
#pragma unroll
        for (int s = 0; s < 2; ++s)
#pragma unroll
            for (int n = 0; n < 4; ++n)
#pragma unroll
                for (int r = 0; r < 4; ++r)
                    redO[(size_t)(qg * 32 + s * 16 + quad * 4 + r) * 64
                         + n * 16 + l15] = o_acc[s][n][r];
        if (l15 == 0) {
#pragma unroll
            for (int s = 0; s < 2; ++s)
#pragma unroll
                for (int r = 0; r < 4; ++r)
                    redL[qg * 32 + s * 16 + quad * 4 + r] = lacc[s][r];
        }
    }
    __syncthreads();
    if (kh == 0) {
#pragma unroll
        for (int s = 0; s < 2; ++s)
#pragma unroll
            for (int r = 0; r < 4; ++r) {
                const int row_l = qg * 32 + s * 16 + quad * 4 + r;
                const float lsum = lacc[s][r] + redL[row_l];
                const float inv = 1.0f / lsum;
                const int row = q0 + row_l;
#pragma unroll
                for (int n = 0; n < 4; ++n) {
                    const float o = o_acc[s][n][r]
                                  + redO[(size_t)row_l * 64 + n * 16 + l15];
                    ctx[(size_t)row * DIM + h * HD + n * 16 + l15] =
                        __float2bfloat16(o * inv);
                }
            }
    }
#undef LOAD_KV
#undef STAGE_KV
}

// ---------------------------------------------------------------------------
// Memory plan (16 MB ws):
//   ws[0 : 8MB]  = Wt_all (4 x bf16 [N][K]: Wq,Wk,Wv,Wo)
//   ws[8 : 16MB] = Q (bf16) -> ctx (in-place, alias-safe)
//   d_out[0:8MB] (bf16) = V scratch; d_out[8:16MB] = K scratch
// x is read directly (fp32) by the fused QKV GEMM — no cast, no alias.
// ---------------------------------------------------------------------------
extern "C" void kernel_launch(void* const* d_in, const int* in_sizes, int n_in,
                              void* d_out, int out_size, void* d_ws, size_t ws_size,
                              hipStream_t stream)
{
    const float* x  = (const float*)d_in[0];
    const float* Wq = (const float*)d_in[1];
    const float* Wk = (const float*)d_in[2];
    const float* Wv = (const float*)d_in[3];
    const float* Wo = (const float*)d_in[4];
    const float* bo = (const float*)d_in[5];
    float* out = (float*)d_out;

    bf16* Wt_all = (bf16*)d_ws;
    bf16* Qb     = Wt_all + (size_t)4 * DIM * DIM;    // ws + 8MB
    bf16* V      = (bf16*)d_out;                      // d_out[0:8MB]
    bf16* Kb     = V + (size_t)SEQ * DIM;             // d_out[8:16MB]
    bf16* ctx    = Qb;                                // in-place over Q
    const bf16* Wot = Wt_all + (size_t)3 * DIM * DIM;

    transpose_cast_kernel<<<dim3(32, 32, 4), 256, 0, stream>>>(Wq, Wk, Wv, Wo, Wt_all);

    qkv_gemm_kernel<<<dim3(DIM / QBN, SEQ / QBM, 3), 256, 0, stream>>>(
        x, Wt_all, Qb, Kb, V);

    flash_attn_kernel<<<dim3(32, NH), 512, 0, stream>>>(Qb, Kb, V, ctx);

    out_gemm_kernel<<<dim3(DIM / 64, SEQ / 128), 256, 0, stream>>>(
        ctx, Wot, bo, out);
}